// Round 3
// baseline (336.379 us; speedup 1.0000x reference)
//
#include <hip/hip_runtime.h>
#include <hip/hip_fp16.h>

#define HID 64
#define ELLK 32   // slots/node; kept degree ~Poisson(5.5), max over 100k ~18
#define CUT_D2 132.5471f   // drop rbf < 1e-5 (R10: measured no absmax change)

typedef _Float16 half8 __attribute__((ext_vector_type(8)));
typedef float f32x4 __attribute__((ext_vector_type(4)));

__device__ __forceinline__ float rbf_of(unsigned w) {
    return __half2float(__ushort_as_half((unsigned short)(w & 0x7fff)));
}

// x16[n][h] = fp16(emb[z[n]][h]); also zeroes ELL counters (rides this kernel).
__global__ void embed_kernel(const int* __restrict__ z, const float* __restrict__ emb,
                             __half* __restrict__ x16, int* __restrict__ cnt, int n) {
    int t = blockIdx.x * blockDim.x + threadIdx.x;
    if (t <= n) cnt[t] = 0;
    if (t >= n * HID / 2) return;
    int node = t >> 5, h2 = (t & 31) * 2;
    const float* src = emb + z[node] * HID + h2;
    __half2 v;
    v.x = __float2half(src[0]);
    v.y = __float2half(src[1]);
    *(__half2*)(x16 + (size_t)node * HID + h2) = v;
}

// ELL fill + fused rbf for KEPT edges; packed record (col<<15)|fp16(rbf).
__global__ void fill_kernel(const int* __restrict__ row, const int* __restrict__ col,
                            const float* __restrict__ pos, int* __restrict__ cnt,
                            unsigned* __restrict__ ell, int e) {
    int t = blockIdx.x * blockDim.x + threadIdx.x;
    if (t >= e) return;
    int r = row[t], c = col[t];
    float dx = pos[3 * r]     - pos[3 * c];
    float dy = pos[3 * r + 1] - pos[3 * c + 1];
    float dz = pos[3 * r + 2] - pos[3 * c + 2];
    float d2 = dx * dx + dy * dy + dz * dz;
    if (d2 > CUT_D2) return;
    float rbf = expf(-sqrtf(d2));
    unsigned short hb = __half_as_ushort(__float2half(rbf));
    int p = atomicAdd(&cnt[r], 1);
    if (p < ELLK) ell[(size_t)r * ELLK + p] = ((unsigned)c << 15) | (unsigned)hb;
}

// R20: fused gather+linear, chunk-major with ZERO inner branches.
// R19 post-mortem: per-pass `if (mcp<=j) continue` guards fragmented the chunk
// into 8 branch blocks; guarded loads can't hoist across branches -> compiler
// scheduled at VGPR=64 with serialized load/FMA blocks (worse than R18).
// R20: the pre-mask already redirects dead slots to (own_row, rbf=0) -> exact
// no-op FMA on a hot line. So process ALL 8 passes to the tile-wide max count
// mcT unconditionally: the chunk body is straight-line 64x {shfl, load, 2 fma},
// letting the compiler issue all loads before consuming (descending vmcnt).
// Dead-slot inflation (~1.5x slot-loads) is own-row L1/L2 hits, not random L3.
// Pre-mask semantics / rounding points / MFMA epilogue unchanged -> bit-identical.
__global__ void layer_kernel(const __half* __restrict__ x16, const int* __restrict__ cnt,
                             const unsigned* __restrict__ ell,
                             const float* __restrict__ W, const float* __restrict__ b,
                             float* __restrict__ out32, __half* __restrict__ out16, int n) {
    __shared__ __align__(16) __half ltile[4][16 * HID];   // 2KB per wave, private
    int tid = threadIdx.x;
    int lane = tid & 63;
    char* tile = (char*)&ltile[tid >> 6][0];

    int hsel = lane & 32;              // gather: 0 = even node lanes, 32 = odd node lanes
    int hbase = (lane & 31) * 2;       // gather: h pair handled by this lane
    int r16 = lane & 15;               // mfma: A row / out col
    int quad = lane >> 4;              // mfma: k-chunk / out row group

    int wid = (blockIdx.x * blockDim.x + tid) >> 6;
    int nw = (gridDim.x * blockDim.x) >> 6;
    int ntiles = (n + 15) >> 4;
    if (wid >= ntiles) return;         // no barriers below -> early-out is safe

    // W fragments + bias preload (HW-verified layout, unchanged from R15 linear)
    half8 bfrag[4][2];
    float biasv[4];
#pragma unroll
    for (int ht = 0; ht < 4; ++ht) {
#pragma unroll
        for (int kt = 0; kt < 2; ++kt) {
            const float* src = W + (ht * 16 + r16) * HID + kt * 32 + quad * 8;
            half8 h;
#pragma unroll
            for (int j = 0; j < 8; ++j) h[j] = (_Float16)src[j];
            bfrag[ht][kt] = h;
        }
        biasv[ht] = b[ht * 16 + r16];
    }

    for (int t = wid; t < ntiles; t += nw) {
        int tbase = t << 4;

        // ---- stage A: counts + all rec rows + all residual rows in flight ----
        int crow = tbase + r16;                       // counts replicated across quads
        int myc = cnt[crow < n ? crow : n - 1];
        if (crow >= n) myc = 0;
        if (myc > ELLK) myc = ELLK;

        unsigned rec[8];
        __half2 res[8];
#pragma unroll
        for (int pp = 0; pp < 8; ++pp) {
            int n0 = tbase + 2 * pp;
            int n0c = n0 < n ? n0 : n - 1;            // clamp (tail slots fully masked)
            rec[pp] = ell[(size_t)n0c * ELLK + lane]; // lanes 0-31: n0; 32-63: n0+1
            int myn = tbase + 2 * pp + (hsel ? 1 : 0);
            if (myn >= n) myn = n - 1;                // clamp (loads only; stores guarded)
            res[pp] = *(const __half2*)(x16 + (size_t)myn * HID + hbase);
        }

        // ---- tile-wide max count (wave-uniform, branchless reduction) ----
        int m = myc;
        m = max(m, __shfl_xor(m, 1));
        m = max(m, __shfl_xor(m, 2));
        m = max(m, __shfl_xor(m, 4));
        m = max(m, __shfl_xor(m, 8));                 // max over each 16-lane group
        int mcT = __builtin_amdgcn_readfirstlane(m);

        // ---- pre-mask: dead slot -> (own row, rbf=0); exact no-op on hot line ----
#pragma unroll
        for (int pp = 0; pp < 8; ++pp) {
            int c_hold = __shfl(myc, 2 * pp + ((lane & 32) ? 1 : 0));
            int hold = tbase + 2 * pp + ((lane & 32) ? 1 : 0);
            if (hold >= n) hold = n - 1;
            if ((lane & 31) >= c_hold)
                rec[pp] = (unsigned)hold << 15;       // rbf bits = 0
        }

        float accx[8], accy[8];
#pragma unroll
        for (int pp = 0; pp < 8; ++pp) {
            accx[pp] = __half2float(res[pp].x);
            accy[pp] = __half2float(res[pp].y);
        }

        // ---- chunk-major gather: straight-line 64 slots/chunk, no branches ----
        for (int j = 0; j < mcT; j += 8) {
#pragma unroll
            for (int pp = 0; pp < 8; ++pp) {
#pragma unroll
                for (int i = 0; i < 8; ++i) {
                    unsigned w = __shfl(rec[pp], hsel + j + i);
                    __half2 v2 = *(const __half2*)(x16 + (size_t)(w >> 15) * HID + hbase);
                    float r = rbf_of(w);              // pre-masked: 0 if dead slot
                    accx[pp] = fmaf(__half2float(v2.x), r, accx[pp]);
                    accy[pp] = fmaf(__half2float(v2.y), r, accy[pp]);
                }
            }
        }

        // ---- y -> swizzled LDS tile (garbage tail rows ok: stores guarded) ----
#pragma unroll
        for (int pp = 0; pp < 8; ++pp) {
            __half2 o;
            o.x = __float2half(accx[pp]);
            o.y = __float2half(accy[pp]);
            int ni = 2 * pp + (hsel ? 1 : 0);
            *(__half2*)(tile + ni * 128 + ((hbase * 2) ^ ((ni & 7) << 4))) = o;
        }

        // ---- phase 2: MFMA on the tile (same-wave LDS RAW: lgkmcnt only) ----
        half8 afrag0 = *(const half8*)(tile + r16 * 128 + ((quad << 4) ^ ((r16 & 7) << 4)));
        half8 afrag1 = *(const half8*)(tile + r16 * 128 + (((quad + 4) << 4) ^ ((r16 & 7) << 4)));
#pragma unroll
        for (int ht = 0; ht < 4; ++ht) {
            f32x4 acc = {biasv[ht], biasv[ht], biasv[ht], biasv[ht]};
            acc = __builtin_amdgcn_mfma_f32_16x16x32_f16(afrag0, bfrag[ht][0], acc, 0, 0, 0);
            acc = __builtin_amdgcn_mfma_f32_16x16x32_f16(afrag1, bfrag[ht][1], acc, 0, 0, 0);
#pragma unroll
            for (int r = 0; r < 4; ++r) {
                int row = tbase + quad * 4 + r;
                if (row < n) {                        // guards garbage tail rows too
                    float v = fmaxf(acc[r], 0.0f);
                    size_t idx = (size_t)row * HID + ht * 16 + r16;
                    if (out32) out32[idx] = v;
                    if (out16) out16[idx] = __float2half(v);
                }
            }
        }
    }
}

extern "C" void kernel_launch(void* const* d_in, const int* in_sizes, int n_in,
                              void* d_out, int out_size, void* d_ws, size_t ws_size,
                              hipStream_t stream) {
    const int*   z    = (const int*)d_in[0];
    const float* pos  = (const float*)d_in[1];
    const int*   eidx = (const int*)d_in[2];
    const float* emb  = (const float*)d_in[3];
    const float* Ws   = (const float*)d_in[4];
    const float* bs   = (const float*)d_in[5];
    int n = in_sizes[0];
    int e = in_sizes[2] / 2;
    int nlayers = in_sizes[4] / (HID * HID);
    const int* row = eidx;
    const int* col = eidx + e;
    float* out = (float*)d_out;

    char* ws = (char*)d_ws;
    __half*   X16 = (__half*)ws;                                   // n*64 fp16 (12.8 MB)
    __half*   Y16 = X16 + (size_t)n * HID;                         // n*64 fp16 (ping-pong)
    unsigned* ell = (unsigned*)((char*)Y16 + (size_t)n * HID * 2); // (n+2)*ELLK u32
    int*      cnt = (int*)((char*)ell + (size_t)(n + 2) * ELLK * 4); // n+1 ints

    // 5 dispatches: embed(+cnt zero), fill, 3x fused layer
    // (R16 lesson: hipLaunchCooperativeKernel does NOT survive this harness's
    // graph capture — remaining ~4 dispatch gaps are structural.)
    embed_kernel<<<(n * HID / 2 + 255) / 256, 256, 0, stream>>>(z, emb, X16, cnt, n);
    fill_kernel<<<(e + 255) / 256, 256, 0, stream>>>(row, col, pos, cnt, ell, e);

    int ntiles = (n + 15) >> 4;
    int lblocks = (ntiles + 3) >> 2;   // 4 waves/block, exactly 1 tile/wave
    for (int l = 0; l < nlayers; ++l) {
        bool last = (l == nlayers - 1);
        const __half* src = (l & 1) ? Y16 : X16;   // ping-pong: fused kernel reads
        __half*       dst = (l & 1) ? X16 : Y16;   // src everywhere while writing dst
        layer_kernel<<<lblocks, 256, 0, stream>>>(src, cnt, ell,
                                                  Ws + (size_t)l * HID * HID,
                                                  bs + (size_t)l * HID,
                                                  last ? out : nullptr,
                                                  last ? nullptr : dst, n);
    }
}

// Round 4
// 272.591 us; speedup vs baseline: 1.2340x; 1.2340x over previous
//
#include <hip/hip_runtime.h>
#include <hip/hip_fp16.h>

#define HID 64
#define ELLK 32   // slots/node; kept degree ~Poisson(5.5), max over 100k ~18
#define CUT_D2 132.5471f   // drop rbf < 1e-5 (R10: measured no absmax change)

typedef _Float16 half8 __attribute__((ext_vector_type(8)));
typedef float f32x4 __attribute__((ext_vector_type(4)));

__device__ __forceinline__ float rbf_of(unsigned w) {
    return __half2float(__ushort_as_half((unsigned short)(w & 0x7fff)));
}

// x16[n][h] = fp16(emb[z[n]][h]); also zeroes ELL counters (rides this kernel).
__global__ void embed_kernel(const int* __restrict__ z, const float* __restrict__ emb,
                             __half* __restrict__ x16, int* __restrict__ cnt, int n) {
    int t = blockIdx.x * blockDim.x + threadIdx.x;
    if (t <= n) cnt[t] = 0;
    if (t >= n * HID / 2) return;
    int node = t >> 5, h2 = (t & 31) * 2;
    const float* src = emb + z[node] * HID + h2;
    __half2 v;
    v.x = __float2half(src[0]);
    v.y = __float2half(src[1]);
    *(__half2*)(x16 + (size_t)node * HID + h2) = v;
}

// ELL fill + fused rbf for KEPT edges; packed record (col<<15)|fp16(rbf).
__global__ void fill_kernel(const int* __restrict__ row, const int* __restrict__ col,
                            const float* __restrict__ pos, int* __restrict__ cnt,
                            unsigned* __restrict__ ell, int e) {
    int t = blockIdx.x * blockDim.x + threadIdx.x;
    if (t >= e) return;
    int r = row[t], c = col[t];
    float dx = pos[3 * r]     - pos[3 * c];
    float dy = pos[3 * r + 1] - pos[3 * c + 1];
    float dz = pos[3 * r + 2] - pos[3 * c + 2];
    float d2 = dx * dx + dy * dy + dz * dz;
    if (d2 > CUT_D2) return;
    float rbf = expf(-sqrtf(d2));
    unsigned short hb = __half_as_ushort(__float2half(rbf));
    int p = atomicAdd(&cnt[r], 1);
    if (p < ELLK) ell[(size_t)r * ELLK + p] = ((unsigned)c << 15) | (unsigned)hb;
}

// R21: fused gather+linear, branchless chunk-major + REGISTER BUDGET FIX.
// R20 post-mortem: WRITE_SIZE=162MB (writes should be 12.5MB) + FETCH+75MB at
// VGPR_Count=64 -> the compiler capped regs for 8-waves/SIMD occupancy and
// SPILLED the accumulators to scratch inside the chunk loop. Persistent state
// (bfrag 32 + biasv 4 + rec 8 + acc 16 + addressing) alone exceeds 64 VGPRs;
// at that budget every schedule is a spill schedule.
// R21 deltas, surgical:
//  (1) __launch_bounds__(256, 4): min 4 waves/EU -> VGPR cap 128. Persistent
//      ~60 regs + in-flight temps now fit without scratch. 16 waves/CU is
//      still ample TLP for 6250 waves.
//  (2) chunk step 4 (was 8): 8 passes x 4 slots = 32 independent loads in
//      flight per chunk, sized to the ~60 free regs (~2/load with saddr form).
// Math path unchanged from R20 -> bit-identical output (absmax 0.00390625).
__global__ void __launch_bounds__(256, 4)
layer_kernel(const __half* __restrict__ x16, const int* __restrict__ cnt,
             const unsigned* __restrict__ ell,
             const float* __restrict__ W, const float* __restrict__ b,
             float* __restrict__ out32, __half* __restrict__ out16, int n) {
    __shared__ __align__(16) __half ltile[4][16 * HID];   // 2KB per wave, private
    int tid = threadIdx.x;
    int lane = tid & 63;
    char* tile = (char*)&ltile[tid >> 6][0];

    int hsel = lane & 32;              // gather: 0 = even node lanes, 32 = odd node lanes
    int hbase = (lane & 31) * 2;       // gather: h pair handled by this lane
    int r16 = lane & 15;               // mfma: A row / out col
    int quad = lane >> 4;              // mfma: k-chunk / out row group

    int wid = (blockIdx.x * blockDim.x + tid) >> 6;
    int nw = (gridDim.x * blockDim.x) >> 6;
    int ntiles = (n + 15) >> 4;
    if (wid >= ntiles) return;         // no barriers below -> early-out is safe

    // W fragments + bias preload (HW-verified layout, unchanged from R15 linear)
    half8 bfrag[4][2];
    float biasv[4];
#pragma unroll
    for (int ht = 0; ht < 4; ++ht) {
#pragma unroll
        for (int kt = 0; kt < 2; ++kt) {
            const float* src = W + (ht * 16 + r16) * HID + kt * 32 + quad * 8;
            half8 h;
#pragma unroll
            for (int j = 0; j < 8; ++j) h[j] = (_Float16)src[j];
            bfrag[ht][kt] = h;
        }
        biasv[ht] = b[ht * 16 + r16];
    }

    for (int t = wid; t < ntiles; t += nw) {
        int tbase = t << 4;

        // ---- stage A: counts + all rec rows + all residual rows in flight ----
        int crow = tbase + r16;                       // counts replicated across quads
        int myc = cnt[crow < n ? crow : n - 1];
        if (crow >= n) myc = 0;
        if (myc > ELLK) myc = ELLK;

        unsigned rec[8];
        __half2 res[8];
#pragma unroll
        for (int pp = 0; pp < 8; ++pp) {
            int n0 = tbase + 2 * pp;
            int n0c = n0 < n ? n0 : n - 1;            // clamp (tail slots fully masked)
            rec[pp] = ell[(size_t)n0c * ELLK + lane]; // lanes 0-31: n0; 32-63: n0+1
            int myn = tbase + 2 * pp + (hsel ? 1 : 0);
            if (myn >= n) myn = n - 1;                // clamp (loads only; stores guarded)
            res[pp] = *(const __half2*)(x16 + (size_t)myn * HID + hbase);
        }

        // ---- tile-wide max count (wave-uniform, branchless reduction) ----
        int m = myc;
        m = max(m, __shfl_xor(m, 1));
        m = max(m, __shfl_xor(m, 2));
        m = max(m, __shfl_xor(m, 4));
        m = max(m, __shfl_xor(m, 8));                 // max over each 16-lane group
        int mcT = __builtin_amdgcn_readfirstlane(m);

        // ---- pre-mask: dead slot -> (own row, rbf=0); exact no-op on hot line ----
#pragma unroll
        for (int pp = 0; pp < 8; ++pp) {
            int c_hold = __shfl(myc, 2 * pp + ((lane & 32) ? 1 : 0));
            int hold = tbase + 2 * pp + ((lane & 32) ? 1 : 0);
            if (hold >= n) hold = n - 1;
            if ((lane & 31) >= c_hold)
                rec[pp] = (unsigned)hold << 15;       // rbf bits = 0
        }

        float accx[8], accy[8];
#pragma unroll
        for (int pp = 0; pp < 8; ++pp) {
            accx[pp] = __half2float(res[pp].x);
            accy[pp] = __half2float(res[pp].y);
        }

        // ---- chunk-major gather: 32 independent loads per chunk, no branches ----
        for (int j = 0; j < mcT; j += 4) {
#pragma unroll
            for (int pp = 0; pp < 8; ++pp) {
#pragma unroll
                for (int i = 0; i < 4; ++i) {
                    unsigned w = __shfl(rec[pp], hsel + j + i);
                    __half2 v2 = *(const __half2*)(x16 + (size_t)(w >> 15) * HID + hbase);
                    float r = rbf_of(w);              // pre-masked: 0 if dead slot
                    accx[pp] = fmaf(__half2float(v2.x), r, accx[pp]);
                    accy[pp] = fmaf(__half2float(v2.y), r, accy[pp]);
                }
            }
        }

        // ---- y -> swizzled LDS tile (garbage tail rows ok: stores guarded) ----
#pragma unroll
        for (int pp = 0; pp < 8; ++pp) {
            __half2 o;
            o.x = __float2half(accx[pp]);
            o.y = __float2half(accy[pp]);
            int ni = 2 * pp + (hsel ? 1 : 0);
            *(__half2*)(tile + ni * 128 + ((hbase * 2) ^ ((ni & 7) << 4))) = o;
        }

        // ---- phase 2: MFMA on the tile (same-wave LDS RAW: lgkmcnt only) ----
        half8 afrag0 = *(const half8*)(tile + r16 * 128 + ((quad << 4) ^ ((r16 & 7) << 4)));
        half8 afrag1 = *(const half8*)(tile + r16 * 128 + (((quad + 4) << 4) ^ ((r16 & 7) << 4)));
#pragma unroll
        for (int ht = 0; ht < 4; ++ht) {
            f32x4 acc = {biasv[ht], biasv[ht], biasv[ht], biasv[ht]};
            acc = __builtin_amdgcn_mfma_f32_16x16x32_f16(afrag0, bfrag[ht][0], acc, 0, 0, 0);
            acc = __builtin_amdgcn_mfma_f32_16x16x32_f16(afrag1, bfrag[ht][1], acc, 0, 0, 0);
#pragma unroll
            for (int r = 0; r < 4; ++r) {
                int row = tbase + quad * 4 + r;
                if (row < n) {                        // guards garbage tail rows too
                    float v = fmaxf(acc[r], 0.0f);
                    size_t idx = (size_t)row * HID + ht * 16 + r16;
                    if (out32) out32[idx] = v;
                    if (out16) out16[idx] = __float2half(v);
                }
            }
        }
    }
}

extern "C" void kernel_launch(void* const* d_in, const int* in_sizes, int n_in,
                              void* d_out, int out_size, void* d_ws, size_t ws_size,
                              hipStream_t stream) {
    const int*   z    = (const int*)d_in[0];
    const float* pos  = (const float*)d_in[1];
    const int*   eidx = (const int*)d_in[2];
    const float* emb  = (const float*)d_in[3];
    const float* Ws   = (const float*)d_in[4];
    const float* bs   = (const float*)d_in[5];
    int n = in_sizes[0];
    int e = in_sizes[2] / 2;
    int nlayers = in_sizes[4] / (HID * HID);
    const int* row = eidx;
    const int* col = eidx + e;
    float* out = (float*)d_out;

    char* ws = (char*)d_ws;
    __half*   X16 = (__half*)ws;                                   // n*64 fp16 (12.8 MB)
    __half*   Y16 = X16 + (size_t)n * HID;                         // n*64 fp16 (ping-pong)
    unsigned* ell = (unsigned*)((char*)Y16 + (size_t)n * HID * 2); // (n+2)*ELLK u32
    int*      cnt = (int*)((char*)ell + (size_t)(n + 2) * ELLK * 4); // n+1 ints

    // 5 dispatches: embed(+cnt zero), fill, 3x fused layer
    // (R16 lesson: hipLaunchCooperativeKernel does NOT survive this harness's
    // graph capture — remaining ~4 dispatch gaps are structural.)
    embed_kernel<<<(n * HID / 2 + 255) / 256, 256, 0, stream>>>(z, emb, X16, cnt, n);
    fill_kernel<<<(e + 255) / 256, 256, 0, stream>>>(row, col, pos, cnt, ell, e);

    int ntiles = (n + 15) >> 4;
    int lblocks = (ntiles + 3) >> 2;   // 4 waves/block, exactly 1 tile/wave
    for (int l = 0; l < nlayers; ++l) {
        bool last = (l == nlayers - 1);
        const __half* src = (l & 1) ? Y16 : X16;   // ping-pong: fused kernel reads
        __half*       dst = (l & 1) ? X16 : Y16;   // src everywhere while writing dst
        layer_kernel<<<lblocks, 256, 0, stream>>>(src, cnt, ell,
                                                  Ws + (size_t)l * HID * HID,
                                                  bs + (size_t)l * HID,
                                                  last ? out : nullptr,
                                                  last ? nullptr : dst, n);
    }
}

// Round 5
// 225.408 us; speedup vs baseline: 1.4923x; 1.2093x over previous
//
#include <hip/hip_runtime.h>
#include <hip/hip_fp16.h>

#define HID 64
#define ELLK 32   // slots/node; kept degree ~Poisson(5.5), max over 100k ~18
#define CUT_D2 132.5471f   // drop rbf < 1e-5 (R10: measured no absmax change)

typedef _Float16 half8 __attribute__((ext_vector_type(8)));
typedef float f32x4 __attribute__((ext_vector_type(4)));

__device__ __forceinline__ float rbf_of(unsigned w) {
    return __half2float(__ushort_as_half((unsigned short)(w & 0x7fff)));
}

// x16[n][h] = fp16(emb[z[n]][h]); also zeroes ELL counters (rides this kernel).
__global__ void embed_kernel(const int* __restrict__ z, const float* __restrict__ emb,
                             __half* __restrict__ x16, int* __restrict__ cnt, int n) {
    int t = blockIdx.x * blockDim.x + threadIdx.x;
    if (t <= n) cnt[t] = 0;
    if (t >= n * HID / 2) return;
    int node = t >> 5, h2 = (t & 31) * 2;
    const float* src = emb + z[node] * HID + h2;
    __half2 v;
    v.x = __float2half(src[0]);
    v.y = __float2half(src[1]);
    *(__half2*)(x16 + (size_t)node * HID + h2) = v;
}

// ELL fill + fused rbf for KEPT edges; packed record (col<<15)|fp16(rbf).
__global__ void fill_kernel(const int* __restrict__ row, const int* __restrict__ col,
                            const float* __restrict__ pos, int* __restrict__ cnt,
                            unsigned* __restrict__ ell, int e) {
    int t = blockIdx.x * blockDim.x + threadIdx.x;
    if (t >= e) return;
    int r = row[t], c = col[t];
    float dx = pos[3 * r]     - pos[3 * c];
    float dy = pos[3 * r + 1] - pos[3 * c + 1];
    float dz = pos[3 * r + 2] - pos[3 * c + 2];
    float d2 = dx * dx + dy * dy + dz * dz;
    if (d2 > CUT_D2) return;
    float rbf = expf(-sqrtf(d2));
    unsigned short hb = __half_as_ushort(__float2half(rbf));
    int p = atomicAdd(&cnt[r], 1);
    if (p < ELLK) ell[(size_t)r * ELLK + p] = ((unsigned)c << 15) | (unsigned)hb;
}

// R22: fused gather+linear — FIT IN 64 VGPRs BY CONSTRUCTION.
// R20/R21 post-mortem: the backend targets 8 waves/SIMD (64 VGPRs) for this
// kernel and SPILLS to keep it — launch_bounds(256,4) only raises the ceiling,
// not the target (WRITE_SIZE 162MB -> 82MB scaled with the in-flight window;
// VGPR_Count pinned at 64 both rounds). So stop fighting the allocator:
//  (1) W fragments (32 persistent VGPRs/lane, replicated per wave) move to
//      block-shared LDS (8KB, frag-major/lane-linear -> stride-1 ds_read_b128).
//      f32->fp16 conversion at preload is the same rounding as before.
//      One __syncthreads BEFORE the early-out (all waves reach it).
//  (2) chunk=2: 16 slot-loads/iter, sized to the ~24 free regs after (1).
//      MLP comes from 8 waves/SIMD occupancy (now achievable spill-free)
//      x modest per-wave ILP, not from a huge register window.
// Slot order / pre-mask no-ops / rounding points unchanged -> bit-identical.
__global__ void layer_kernel(const __half* __restrict__ x16, const int* __restrict__ cnt,
                             const unsigned* __restrict__ ell,
                             const float* __restrict__ W, const float* __restrict__ b,
                             float* __restrict__ out32, __half* __restrict__ out16, int n) {
    __shared__ __align__(16) __half ltile[4][16 * HID];   // 2KB per wave, private
    __shared__ __align__(16) __half wlds[8][64][8];       // 8KB: [frag][lane][8 halves]
    int tid = threadIdx.x;
    int lane = tid & 63;
    char* tile = (char*)&ltile[tid >> 6][0];

    int hsel = lane & 32;              // gather: 0 = even node lanes, 32 = odd node lanes
    int hbase = (lane & 31) * 2;       // gather: h pair handled by this lane
    int r16 = lane & 15;               // mfma: A row / out col
    int quad = lane >> 4;              // mfma: k-chunk / out row group

    // ---- W -> LDS preload (block-cooperative, 512 frag-slots, 2/thread) ----
#pragma unroll
    for (int s0 = 0; s0 < 2; ++s0) {
        int s = tid + s0 * 256;                    // s = f*64 + l
        int f = s >> 6, l = s & 63;
        int ht = f >> 1, kt = f & 1, q = l >> 4, r = l & 15;
        const float* src = W + (ht * 16 + r) * HID + kt * 32 + q * 8;
        half8 h;
#pragma unroll
        for (int j = 0; j < 8; ++j) h[j] = (_Float16)src[j];
        *(half8*)&wlds[f][l][0] = h;
    }
    float biasv[4];
#pragma unroll
    for (int ht = 0; ht < 4; ++ht) biasv[ht] = b[ht * 16 + r16];
    __syncthreads();                               // before early-out: all waves arrive

    int wid = (blockIdx.x * blockDim.x + tid) >> 6;
    int nw = (gridDim.x * blockDim.x) >> 6;
    int ntiles = (n + 15) >> 4;
    if (wid >= ntiles) return;                     // no barriers below -> safe

    const half8* wl = (const half8*)&wlds[0][0][0];

    for (int t = wid; t < ntiles; t += nw) {
        int tbase = t << 4;

        // ---- stage A: counts + all rec rows + all residual rows in flight ----
        int crow = tbase + r16;                       // counts replicated across quads
        int myc = cnt[crow < n ? crow : n - 1];
        if (crow >= n) myc = 0;
        if (myc > ELLK) myc = ELLK;

        unsigned rec[8];
        __half2 res[8];
#pragma unroll
        for (int pp = 0; pp < 8; ++pp) {
            int n0 = tbase + 2 * pp;
            int n0c = n0 < n ? n0 : n - 1;            // clamp (tail slots fully masked)
            rec[pp] = ell[(size_t)n0c * ELLK + lane]; // lanes 0-31: n0; 32-63: n0+1
            int myn = tbase + 2 * pp + (hsel ? 1 : 0);
            if (myn >= n) myn = n - 1;                // clamp (loads only; stores guarded)
            res[pp] = *(const __half2*)(x16 + (size_t)myn * HID + hbase);
        }

        // ---- tile-wide max count (wave-uniform, branchless reduction) ----
        int m = myc;
        m = max(m, __shfl_xor(m, 1));
        m = max(m, __shfl_xor(m, 2));
        m = max(m, __shfl_xor(m, 4));
        m = max(m, __shfl_xor(m, 8));                 // max over each 16-lane group
        int mcT = __builtin_amdgcn_readfirstlane(m);

        // ---- pre-mask: dead slot -> (own row, rbf=0); exact no-op on hot line ----
#pragma unroll
        for (int pp = 0; pp < 8; ++pp) {
            int c_hold = __shfl(myc, 2 * pp + ((lane & 32) ? 1 : 0));
            int hold = tbase + 2 * pp + ((lane & 32) ? 1 : 0);
            if (hold >= n) hold = n - 1;
            if ((lane & 31) >= c_hold)
                rec[pp] = (unsigned)hold << 15;       // rbf bits = 0
        }

        float accx[8], accy[8];
#pragma unroll
        for (int pp = 0; pp < 8; ++pp) {
            accx[pp] = __half2float(res[pp].x);
            accy[pp] = __half2float(res[pp].y);
        }

        // ---- chunk-major gather: 16 loads/iter, sized to the free-reg budget ----
        for (int j = 0; j < mcT; j += 2) {
#pragma unroll
            for (int pp = 0; pp < 8; ++pp) {
#pragma unroll
                for (int i = 0; i < 2; ++i) {
                    unsigned w = __shfl(rec[pp], hsel + j + i);
                    __half2 v2 = *(const __half2*)(x16 + (size_t)(w >> 15) * HID + hbase);
                    float r = rbf_of(w);              // pre-masked: 0 if dead slot
                    accx[pp] = fmaf(__half2float(v2.x), r, accx[pp]);
                    accy[pp] = fmaf(__half2float(v2.y), r, accy[pp]);
                }
            }
        }

        // ---- y -> swizzled LDS tile (garbage tail rows ok: stores guarded) ----
#pragma unroll
        for (int pp = 0; pp < 8; ++pp) {
            __half2 o;
            o.x = __float2half(accx[pp]);
            o.y = __float2half(accy[pp]);
            int ni = 2 * pp + (hsel ? 1 : 0);
            *(__half2*)(tile + ni * 128 + ((hbase * 2) ^ ((ni & 7) << 4))) = o;
        }

        // ---- phase 2: MFMA; A-frags from wave tile, B-frags from block W-LDS ----
        half8 afrag0 = *(const half8*)(tile + r16 * 128 + ((quad << 4) ^ ((r16 & 7) << 4)));
        half8 afrag1 = *(const half8*)(tile + r16 * 128 + (((quad + 4) << 4) ^ ((r16 & 7) << 4)));
#pragma unroll
        for (int ht = 0; ht < 4; ++ht) {
            f32x4 acc = {biasv[ht], biasv[ht], biasv[ht], biasv[ht]};
            half8 b0 = wl[(ht * 2 + 0) * 64 + lane];  // stride-1 ds_read_b128
            half8 b1 = wl[(ht * 2 + 1) * 64 + lane];
            acc = __builtin_amdgcn_mfma_f32_16x16x32_f16(afrag0, b0, acc, 0, 0, 0);
            acc = __builtin_amdgcn_mfma_f32_16x16x32_f16(afrag1, b1, acc, 0, 0, 0);
#pragma unroll
            for (int r = 0; r < 4; ++r) {
                int row = tbase + quad * 4 + r;
                if (row < n) {                        // guards garbage tail rows too
                    float v = fmaxf(acc[r], 0.0f);
                    size_t idx = (size_t)row * HID + ht * 16 + r16;
                    if (out32) out32[idx] = v;
                    if (out16) out16[idx] = __float2half(v);
                }
            }
        }
    }
}

extern "C" void kernel_launch(void* const* d_in, const int* in_sizes, int n_in,
                              void* d_out, int out_size, void* d_ws, size_t ws_size,
                              hipStream_t stream) {
    const int*   z    = (const int*)d_in[0];
    const float* pos  = (const float*)d_in[1];
    const int*   eidx = (const int*)d_in[2];
    const float* emb  = (const float*)d_in[3];
    const float* Ws   = (const float*)d_in[4];
    const float* bs   = (const float*)d_in[5];
    int n = in_sizes[0];
    int e = in_sizes[2] / 2;
    int nlayers = in_sizes[4] / (HID * HID);
    const int* row = eidx;
    const int* col = eidx + e;
    float* out = (float*)d_out;

    char* ws = (char*)d_ws;
    __half*   X16 = (__half*)ws;                                   // n*64 fp16 (12.8 MB)
    __half*   Y16 = X16 + (size_t)n * HID;                         // n*64 fp16 (ping-pong)
    unsigned* ell = (unsigned*)((char*)Y16 + (size_t)n * HID * 2); // (n+2)*ELLK u32
    int*      cnt = (int*)((char*)ell + (size_t)(n + 2) * ELLK * 4); // n+1 ints

    // 5 dispatches: embed(+cnt zero), fill, 3x fused layer
    // (R16 lesson: hipLaunchCooperativeKernel does NOT survive this harness's
    // graph capture — remaining ~4 dispatch gaps are structural.)
    embed_kernel<<<(n * HID / 2 + 255) / 256, 256, 0, stream>>>(z, emb, X16, cnt, n);
    fill_kernel<<<(e + 255) / 256, 256, 0, stream>>>(row, col, pos, cnt, ell, e);

    int ntiles = (n + 15) >> 4;
    int lblocks = (ntiles + 3) >> 2;   // 4 waves/block, exactly 1 tile/wave
    for (int l = 0; l < nlayers; ++l) {
        bool last = (l == nlayers - 1);
        const __half* src = (l & 1) ? Y16 : X16;   // ping-pong: fused kernel reads
        __half*       dst = (l & 1) ? X16 : Y16;   // src everywhere while writing dst
        layer_kernel<<<lblocks, 256, 0, stream>>>(src, cnt, ell,
                                                  Ws + (size_t)l * HID * HID,
                                                  bs + (size_t)l * HID,
                                                  last ? out : nullptr,
                                                  last ? nullptr : dst, n);
    }
}